// Round 1
// baseline (87.229 us; speedup 1.0000x reference)
//
#include <hip/hip_runtime.h>

// QuantumLSTMCell: B=1M rows. Per row: u = W*x+b; joint = outer(u,h)/(|u||h|);
// psi = C*joint; p = psi^2; h_next[a] = sum_s p[4s+a]; out = sum_r z_r p_r.
// C is a fixed 16x16 built from 16 angles. Folded: psi_r*|u||h| = x*(A_r.h)+(Bm_r.h).

__device__ __forceinline__ int ring_perm(int k) {
  // CNOT(0,1), CNOT(1,2), CNOT(2,3), CNOT(3,0) applied in sequence; wire 0 = MSB.
  int b0 = (k >> 3) & 1, b1 = (k >> 2) & 1, b2 = (k >> 1) & 1, b3 = k & 1;
  b1 ^= b0; b2 ^= b1; b3 ^= b2; b0 ^= b3;
  return (b0 << 3) | (b1 << 2) | (b2 << 1) | b3;
}

__global__ __launch_bounds__(256) void build_consts_kernel(
    const float* __restrict__ W_in, const float* __restrict__ b_in,
    const float* __restrict__ U, const float* __restrict__ Ud,
    float* __restrict__ ws) {
  __shared__ float M[16][16];   // running product
  __shared__ float Lm[16][16];  // current layer unitary
  const int t = threadIdx.x;
  const int i = t >> 4, j = t & 15;
  const int pi = ring_perm(i);

  // weights order: U[0], U[1], Udagger[1], Udagger[0]
  float ang[4][4];
#pragma unroll
  for (int q = 0; q < 4; ++q) {
    ang[0][q] = U[q];
    ang[1][q] = U[4 + q];
    ang[2][q] = Ud[4 + q];
    ang[3][q] = Ud[q];
  }

  // layer 0: M = RING @ kron(RY(w0)..RY(w3))  (scatter through perm)
  {
    float kel = 1.f;
#pragma unroll
    for (int q = 0; q < 4; ++q) {
      float c = cosf(0.5f * ang[0][q]);
      float s = sinf(0.5f * ang[0][q]);
      int iq = (i >> (3 - q)) & 1, jq = (j >> (3 - q)) & 1;
      kel *= (iq == jq) ? c : (iq ? s : -s);
    }
    M[pi][j] = kel;
  }
  __syncthreads();

  for (int l = 1; l < 4; ++l) {
    float kel = 1.f;
#pragma unroll
    for (int q = 0; q < 4; ++q) {
      float c = cosf(0.5f * ang[l][q]);
      float s = sinf(0.5f * ang[l][q]);
      int iq = (i >> (3 - q)) & 1, jq = (j >> (3 - q)) & 1;
      kel *= (iq == jq) ? c : (iq ? s : -s);
    }
    Lm[pi][j] = kel;
    __syncthreads();
    float acc = 0.f;
#pragma unroll
    for (int k = 0; k < 16; ++k) acc += Lm[i][k] * M[k][j];
    __syncthreads();  // all reads of M done before overwrite
    M[i][j] = acc;
    __syncthreads();
  }

  // A[r][k] = sum_i W_i * C[r][4i+k] ; Bm likewise with b_i
  if (t < 64) {
    const int r = t >> 2, k = t & 3;
    float a = 0.f, bb = 0.f;
#pragma unroll
    for (int q = 0; q < 4; ++q) {
      float c = M[r][4 * q + k];
      a = fmaf(W_in[q], c, a);
      bb = fmaf(b_in[q], c, bb);
    }
    ws[r * 4 + k] = a;
    ws[64 + r * 4 + k] = bb;
  }
  if (t == 0) {
    float qa = 0.f, qb = 0.f, qc = 0.f;
#pragma unroll
    for (int q = 0; q < 4; ++q) {
      qa = fmaf(W_in[q], W_in[q], qa);
      qb = fmaf(2.f * W_in[q], b_in[q], qb);
      qc = fmaf(b_in[q], b_in[q], qc);
    }
    ws[128] = qa; ws[129] = qb; ws[130] = qc;
  }
}

__global__ __launch_bounds__(256) void qlstm_kernel(
    const float* __restrict__ x, const float4* __restrict__ h_prev,
    const float* __restrict__ AB, float4* __restrict__ h_next,
    float* __restrict__ outp, int B) {
  int gid = blockIdx.x * 256 + threadIdx.x;
  if (gid >= B) return;
  float xv = x[gid];
  float4 h = h_prev[gid];
  float nh2 = fmaf(h.x, h.x, fmaf(h.y, h.y, fmaf(h.z, h.z, h.w * h.w)));
  float qa = AB[128], qb = AB[129], qc = AB[130];
  float nu2 = fmaf(fmaf(qa, xv, qb), xv, qc);
  float inv2 = __builtin_amdgcn_rcpf(nu2 * nh2);  // 1/(|u|^2 |h|^2), both > 0

  float hn[4] = {0.f, 0.f, 0.f, 0.f};
  float po = 0.f;
#pragma unroll
  for (int r = 0; r < 16; ++r) {
    float ar = fmaf(AB[r * 4 + 0], h.x,
               fmaf(AB[r * 4 + 1], h.y,
               fmaf(AB[r * 4 + 2], h.z, AB[r * 4 + 3] * h.w)));
    float br = fmaf(AB[64 + r * 4 + 0], h.x,
               fmaf(AB[64 + r * 4 + 1], h.y,
               fmaf(AB[64 + r * 4 + 2], h.z, AB[64 + r * 4 + 3] * h.w)));
    float tr = fmaf(xv, ar, br);
    float s = tr * tr;
    hn[r & 3] += s;
    po += ((r >> 2) & 1) ? -s : s;
  }
  float4 o;
  o.x = hn[0] * inv2;
  o.y = hn[1] * inv2;
  o.z = hn[2] * inv2;
  o.w = hn[3] * inv2;
  h_next[gid] = o;
  outp[gid] = po * inv2;
}

extern "C" void kernel_launch(void* const* d_in, const int* in_sizes, int n_in,
                              void* d_out, int out_size, void* d_ws, size_t ws_size,
                              hipStream_t stream) {
  const float* x  = (const float*)d_in[0];
  const float* h  = (const float*)d_in[1];
  const float* W  = (const float*)d_in[2];
  const float* bi = (const float*)d_in[3];
  const float* U  = (const float*)d_in[4];
  const float* Ud = (const float*)d_in[5];
  float* ws = (float*)d_ws;
  const int B = in_sizes[0];
  float* h_next = (float*)d_out;
  float* out1   = (float*)d_out + 4 * (size_t)B;

  build_consts_kernel<<<1, 256, 0, stream>>>(W, bi, U, Ud, ws);
  qlstm_kernel<<<(B + 255) / 256, 256, 0, stream>>>(
      x, (const float4*)h, ws, (float4*)h_next, out1, B);
}